// Round 15
// baseline (147.559 us; speedup 1.0000x reference)
//
#include <hip/hip_runtime.h>
#include <hip/hip_bf16.h>

#define Tn 512
#define Bn 512
#define Kn 128
#define NUMCH 16    // numerator t-chunks (32 t each)
#define NEXPEM 4096 // expem grid blocks

typedef __bf16 bf16_t;
typedef __bf16 bf16x8 __attribute__((ext_vector_type(8)));
typedef float f32x4 __attribute__((ext_vector_type(4)));
typedef unsigned int u32;
typedef u32 u32x2 __attribute__((ext_vector_type(2)));
typedef u32 u32x4 __attribute__((ext_vector_type(4)));

__device__ __forceinline__ u32 pack2bf(float a, float b) {
    bf16_t ha = (bf16_t)a, hb = (bf16_t)b;
    u32 ua = (u32)__builtin_bit_cast(unsigned short, ha);
    u32 ub = (u32)__builtin_bit_cast(unsigned short, hb);
    return ua | (ub << 16);
}

// ---------------- small pre: numerator partials (0..31, coalesced) +
//                  frag build (32..159) + out zeroing.  ~4us (r12-verified) ----------
// A-frag image: idx = (((dir*8 + m)*4 + ks)*64 + l)*8 + e
//   lane roles: c=l&15, g=l>>4;  k = 32*ks + 8*g + e
//   row j = J(m,c) = 32*(m>>1) + 4*(m&1) + 8*(c>>2) + (c&3)
//   dir 0 (fwd): A[j][k] = exp(trans[k][j]);  dir 1 (bwd): A[j][k] = exp(trans[j][k])
// J chosen so D's per-lane output IS the next step's B-frag layout (verified r1-r14).
__global__ __launch_bounds__(256)
void crf_small(const float* __restrict__ em, const int* __restrict__ tags,
               const int* __restrict__ mask, const float* __restrict__ trans,
               bf16_t* __restrict__ frags, float* __restrict__ numpart,
               int* __restrict__ cntpart, float* __restrict__ out)
{
    const int bid = blockIdx.x;
    const int tid = threadIdx.x;

    if (bid < 2*NUMCH) {               // ---- numerator partials, coalesced over b ----
        const int ch = bid >> 1, bh = bid & 1;
        const int b  = bh*256 + tid;   // lane-adjacent b -> coalesced mask/tags loads
        const int t0 = ch * (Tn / NUMCH);
        float s = 0.f;
        int cnt = 0;
        int tagprev = (t0 > 0) ? tags[(t0-1)*Bn + b] : 0;
        for (int t = t0; t < t0 + Tn/NUMCH; ++t) {
            const int mk = mask[t*Bn + b];
            const int tagcur = tags[t*Bn + b];
            if (mk != 0) {
                cnt++;
                if (t >= 1)
                    s += trans[tagprev*Kn + tagcur]
                       + em[(size_t)t*Bn*Kn + (size_t)b*Kn + tagcur];
            }
            tagprev = tagcur;
        }
        numpart[ch*Bn + b] = s;
        cntpart[ch*Bn + b] = cnt;
        return;
    }

    // ---- frag build: 128 blocks x 256 threads = 32768 elements ----
    const int b2 = bid - 2*NUMCH;
    if (b2 == 0 && tid == 0) out[0] = 0.f;
    const int idx = b2*256 + tid;
    const int e   = idx & 7;
    const int l   = (idx >> 3) & 63;
    const int ks  = (idx >> 9) & 3;
    const int m   = (idx >> 11) & 7;
    const int dir = (idx >> 14) & 1;
    const int c = l & 15, g = l >> 4;
    const int k = 32*ks + 8*g + e;
    const int j = 32*(m >> 1) + 4*(m & 1) + 8*(c >> 2) + (c & 3);
    const float v = (dir == 0) ? trans[k*Kn + j] : trans[j*Kn + k];
    frags[idx] = (bf16_t)__expf(v);
}

// ---------------- expem: X = bf16(exp(em)) — STANDALONE (r8-verified ~30us) ----------
// Fused-into-pre variants ran 81-89us with identical inner code (r11/r13/r14);
// standalone r8 form ran ~30us. Kept as its own kernel deliberately.
__global__ __launch_bounds__(256)
void crf_expem(const float* __restrict__ em, u32* __restrict__ X)
{
    const size_t N = (size_t)Tn * Bn * Kn;
    const size_t nth = (size_t)gridDim.x * blockDim.x;
    for (size_t base = ((size_t)blockIdx.x * blockDim.x + threadIdx.x) * 8; base < N;
         base += nth * 8) {
        const f32x4 a = *reinterpret_cast<const f32x4*>(em + base);
        const f32x4 b = *reinterpret_cast<const f32x4*>(em + base + 4);
        u32x4 w;
        w[0] = pack2bf(__expf(a[0]), __expf(a[1]));
        w[1] = pack2bf(__expf(a[2]), __expf(a[3]));
        w[2] = pack2bf(__expf(b[0]), __expf(b[1]));
        w[3] = pack2bf(__expf(b[2]), __expf(b[3]));
        *reinterpret_cast<u32x4*>(X + base / 2) = w;
    }
}

// ---------------- main: 8-wave j-split recurrence (r11/r14 body, X path) ------------
// 64 blocks x 512 threads (8 waves = 2 waves/SIMD on 64 CUs). Wave mw owns m-tile mw
// (4 MFMA as 2 independent 2-chains + add), produces 4 j's/lane (u32x2 b64 write).
// State exchange: 8KB double-buffered LDS, one raw s_barrier/step. t-advance via
// uniform (SALU) offsets + constant per-lane 32-bit offsets. X = bf16(exp(em)):
// halves main's streamed bytes (main's effective fetch rate is the binding cap).
template<int PRE>
__global__ __launch_bounds__(512, 1)
void crf_main(const float* __restrict__ em, const u32* __restrict__ Xp,
              const int* __restrict__ maskp,
              const float* __restrict__ startT, const float* __restrict__ endT,
              const bf16_t* __restrict__ frags,
              float* __restrict__ vws, float* __restrict__ Cws)
{
    const int bid = blockIdx.x;          // 64 blocks
    const int dir = bid & 1;
    const int b0  = (bid >> 1) * 16;
    const int tid = threadIdx.x;
    const int mw  = tid >> 6;            // wave id = m-tile index 0..7
    const int l   = tid & 63;
    const int c = l & 15, g = l >> 4;
    const int batch = b0 + c;
    const int ksw  = mw >> 1, half = mw & 1;
    const int bj   = 32*ksw + 4*half;    // base j of own 4 outputs (plus 8g)

    __shared__ __align__(16) u32x4 exchg[2][4][64];   // [parity][slice][lane]

    // resident E fragments for own m-tile
    bf16x8 af[4];
    {
        const bf16_t* fb = frags + (size_t)dir * 16384;
        #pragma unroll
        for (int ks = 0; ks < 4; ++ks)
            af[ks] = *reinterpret_cast<const bf16x8*>(fb + ((mw*4 + ks)*64 + l)*8);
    }

    // init own state (+ bwd f32 state)
    f32x4 up;
    u32 ownprev0, ownprev1;
    float Cacc = 0.f;
    {
        const float* sv = dir ? endT : startT;
        const int t0 = dir ? 511 : 0;
        const f32x4 e4 = *reinterpret_cast<const f32x4*>(
            em + ((size_t)t0*Bn + batch)*Kn + bj + 8*g);
        const float* s4p = sv + bj + 8*g;
        f32x4 y;
        #pragma unroll
        for (int r = 0; r < 4; ++r) {
            const float s = s4p[r];
            y[r]  = __expf(s + e4[r]);
            up[r] = __expf(s);
        }
        ownprev0 = pack2bf(y[0], y[1]);
        ownprev1 = pack2bf(y[2], y[3]);
        u32* slot = reinterpret_cast<u32*>(&exchg[1][ksw][l]) + 2*half;
        u32x2 nw2 = {ownprev0, ownprev1};
        *reinterpret_cast<u32x2*>(slot) = nw2;   // iter m=1 reads parity 1
    }

    const int M = 256 - dir;

    // constant per-lane offsets (32-bit) + uniform t-offsets advanced on SALU
    const u32 laneX = (u32)(((batch*Kn) + bj + 8*g) >> 1);   // u32-index into X
    const u32 laneE = (u32)((batch*Kn) + bj + 8*g);          // f32-index into em
    const u32 laneM = (u32)batch;                            // int-index into mask
    const long stepX = dir ? -(long)(Bn*Kn)   : (long)(Bn*Kn);     // per 2t (u32 units)
    const long stepE = dir ? -(long)(2*Bn*Kn) : (long)(2*Bn*Kn);   // per 2t (f32 units)
    const long stepM = dir ? -(long)(2*Bn)    : (long)(2*Bn);      // per 2t (int units)
    long uXA, uXB, uEA, uEB, uMA, uMB;
    {
        const int tA  = dir ? 510 : 1, tB  = dir ? 509 : 2;
        const int tmA = dir ? 511 : 1, tmB = dir ? 510 : 2;
        uXA = (long)tA * (Bn*Kn/2);  uXB = (long)tB * (Bn*Kn/2);
        uEA = (long)tA * (Bn*Kn);    uEB = (long)tB * (Bn*Kn);
        uMA = (long)tmA * Bn;        uMB = (long)tmB * Bn;
    }

    u32x2 xA, xB; f32x4 eA, eB; int mkA, mkB;
    auto load_tile = [&](u32x2& xd, f32x4& ed, int& mk, long& uX, long& uE, long& uM) {
        if (PRE) { xd = *reinterpret_cast<const u32x2*>(Xp + uX + laneX); uX += stepX; }
        else     { ed = *reinterpret_cast<const f32x4*>(em + uE + laneE); uE += stepE; }
        mk = maskp[uM + laneM]; uM += stepM;
    };

    auto iter = [&](u32x2& xcur, f32x4& ecur, int& mkcur,
                    long& uX, long& uE, long& uM, bool rs, int par) {
        // release own write of previous step, sync, read full state
        asm volatile("s_waitcnt lgkmcnt(0)" ::: "memory");
        __builtin_amdgcn_s_barrier();
        __builtin_amdgcn_sched_barrier(0);

        const u32x4 bs0 = exchg[par][0][l];
        const u32x4 bs1 = exchg[par][1][l];
        const u32x4 bs2 = exchg[par][2][l];
        const u32x4 bs3 = exchg[par][3][l];

        // 2 independent MFMA chains of 2, then add (halves serial MFMA latency)
        f32x4 a0 = {0.f, 0.f, 0.f, 0.f}, a1 = {0.f, 0.f, 0.f, 0.f};
        a0 = __builtin_amdgcn_mfma_f32_16x16x32_bf16(af[0], __builtin_bit_cast(bf16x8, bs0), a0, 0, 0, 0);
        a1 = __builtin_amdgcn_mfma_f32_16x16x32_bf16(af[2], __builtin_bit_cast(bf16x8, bs2), a1, 0, 0, 0);
        a0 = __builtin_amdgcn_mfma_f32_16x16x32_bf16(af[1], __builtin_bit_cast(bf16x8, bs1), a0, 0, 0, 0);
        a1 = __builtin_amdgcn_mfma_f32_16x16x32_bf16(af[3], __builtin_bit_cast(bf16x8, bs3), a1, 0, 0, 0);
        const f32x4 acc = a0 + a1;

        const bool mk = (mkcur != 0);
        float sc = 1.f, klog = 0.f;
        if (rs) {   // exact pow-2 rescale; exponent of batch c's k=0 state component
            int ex = (int)((bs0[0] >> 7) & 0xFF) - 127;
            ex = __shfl(ex, c, 64);
            sc = __uint_as_float((u32)((127 - ex) & 0xFF) << 23);
            klog = (float)ex * 0.6931471805599453f;
        }

        f32x4 xf;
        if (PRE) {
            xf[0] = __uint_as_float(xcur[0] << 16);
            xf[1] = __uint_as_float(xcur[0] & 0xffff0000u);
            xf[2] = __uint_as_float(xcur[1] << 16);
            xf[3] = __uint_as_float(xcur[1] & 0xffff0000u);
        } else {
            #pragma unroll
            for (int r = 0; r < 4; ++r) xf[r] = __expf(ecur[r]);
        }

        u32 nw0, nw1;
        if (dir == 0) {  // fwd: v_t = (v@E)*x_t if mask else v
            f32x4 y;
            #pragma unroll
            for (int r = 0; r < 4; ++r) {
                float a = acc[r];
                if (rs) a *= sc;
                y[r] = a * xf[r];
            }
            nw0 = pack2bf(y[0], y[1]);
            nw1 = pack2bf(y[2], y[3]);
            nw0 = mk ? nw0 : ownprev0;
            nw1 = mk ? nw1 : ownprev1;
            ownprev0 = nw0; ownprev1 = nw1;
            if (rs && mk) Cacc += klog;
        } else {  // bwd: u = select(E@B, u); scale both branches; B = u*x_t
            f32x4 y;
            #pragma unroll
            for (int r = 0; r < 4; ++r) {
                float un = mk ? acc[r] : up[r];
                if (rs) un *= sc;
                up[r] = un;
                y[r] = un * xf[r];
            }
            nw0 = pack2bf(y[0], y[1]);
            nw1 = pack2bf(y[2], y[3]);
            if (rs) Cacc += klog;
        }

        u32* slot = reinterpret_cast<u32*>(&exchg[par ^ 1][ksw][l]) + 2*half;
        u32x2 nw2 = {nw0, nw1};
        *reinterpret_cast<u32x2*>(slot) = nw2;

        load_tile(xcur, ecur, mkcur, uX, uE, uM);
        __builtin_amdgcn_sched_barrier(0xF); // ALU/VALU/SALU/MFMA may cross; VMEM+DS pinned
    };

    load_tile(xA, eA, mkA, uXA, uEA, uMA);
    load_tile(xB, eB, mkB, uXB, uEB, uMB);
    __builtin_amdgcn_sched_barrier(0xF);

    int m = 1;
    for (; m + 3 <= M; m += 4) {       // rs static: only (m+3)%4==0 rescales; par static
        iter(xA, eA, mkA, uXA, uEA, uMA, false, 1);
        iter(xB, eB, mkB, uXB, uEB, uMB, false, 0);
        iter(xA, eA, mkA, uXA, uEA, uMA, false, 1);
        iter(xB, eB, mkB, uXB, uEB, uMB, true,  0);
    }
    for (; m <= M; ++m) {              // bwd tail m=253..255 (never a rescale step)
        if (m & 1) iter(xA, eA, mkA, uXA, uEA, uMA, false, 1);
        else       iter(xB, eB, mkB, uXB, uEB, uMB, false, 0);
    }

    // final own state: fwd from ownprev regs, bwd from f32 up
    float* vrow = vws + ((size_t)(dir*Bn + batch))*Kn + bj + 8*g;
    f32x4 fv;
    if (dir) {
        fv = up;
    } else {
        fv[0] = __uint_as_float(ownprev0 << 16);
        fv[1] = __uint_as_float(ownprev0 & 0xffff0000u);
        fv[2] = __uint_as_float(ownprev1 << 16);
        fv[3] = __uint_as_float(ownprev1 & 0xffff0000u);
    }
    *reinterpret_cast<f32x4*>(vrow) = fv;
    if (mw == 0 && g == 0) Cws[dir*Bn + batch] = Cacc;
}

// ---------------- combine: numerator finalize + den + out accumulation ----------------
__global__ void crf_combine(const float* __restrict__ vws, const float* __restrict__ Cws,
                            const float* __restrict__ numpart, const int* __restrict__ cntpart,
                            const int* __restrict__ tags, const float* __restrict__ em,
                            const float* __restrict__ startT, const float* __restrict__ endT,
                            float* __restrict__ out)
{
    const int b = blockIdx.x;
    const int tid = threadIdx.x;
    const float p = vws[(size_t)b*Kn + tid] * vws[(size_t)(Bn + b)*Kn + tid];
    __shared__ float red[128];
    __shared__ float sp[NUMCH];
    __shared__ int   cp[NUMCH];
    red[tid] = p;
    if (tid < NUMCH) { sp[tid] = numpart[tid*Bn + b]; cp[tid] = cntpart[tid*Bn + b]; }
    __syncthreads();
    for (int off = 64; off > 0; off >>= 1) {
        if (tid < off) red[tid] += red[tid + off];
        __syncthreads();
    }
    if (tid == 0) {
        float s = 0.f; int cnt = 0;
        #pragma unroll
        for (int ch = 0; ch < NUMCH; ++ch) { s += sp[ch]; cnt += cp[ch]; }
        const int t0tag = tags[b];
        int seq_end = cnt - 1;
        if (seq_end < 0) seq_end = 0;
        const int lastTag = tags[seq_end*Bn + b];
        const float num = startT[t0tag] + em[(size_t)b*Kn + t0tag] + s + endT[lastTag];
        const float den = Cws[b] + Cws[Bn + b] + logf(red[0]);
        atomicAdd(out, num - den);
    }
}

extern "C" void kernel_launch(void* const* d_in, const int* in_sizes, int n_in,
                              void* d_out, int out_size, void* d_ws, size_t ws_size,
                              hipStream_t stream)
{
    const float* em     = (const float*)d_in[0];
    const int*   tags   = (const int*)d_in[1];
    const int*   mask   = (const int*)d_in[2];
    const float* startT = (const float*)d_in[3];
    const float* endT   = (const float*)d_in[4];
    const float* trans  = (const float*)d_in[5];

    const size_t XBYTES = (size_t)Tn * Bn * Kn * 2;   // 33.5 MB
    const size_t SMALL  = 65536 + 4096 + 524288 + 32768 + 32768;
    const bool pre = (ws_size >= XBYTES + SMALL);

    char* ws = (char*)d_ws;
    u32*  X  = (u32*)ws;                              // PRE path only
    char* base = pre ? (ws + XBYTES) : ws;
    bf16_t* frags   = (bf16_t*)base;                  // 65536 B
    float*  Cws     = (float*)(base + 65536);         // 4096 B
    float*  vws     = (float*)(base + 69632);         // 524288 B
    float*  numpart = (float*)(base + 593920);        // 32768 B
    int*    cntpart = (int*)(base + 626688);          // 32768 B
    float*  out     = (float*)d_out;

    hipLaunchKernelGGL(crf_small, dim3(2*NUMCH + 128), dim3(256), 0, stream,
                       em, tags, mask, trans, frags, numpart, cntpart, out);
    if (pre) {
        hipLaunchKernelGGL(crf_expem, dim3(NEXPEM), dim3(256), 0, stream, em, X);
        hipLaunchKernelGGL((crf_main<1>), dim3(64), dim3(512), 0, stream,
                           em, X, mask, startT, endT, frags, vws, Cws);
    } else {
        hipLaunchKernelGGL((crf_main<0>), dim3(64), dim3(512), 0, stream,
                           em, X, mask, startT, endT, frags, vws, Cws);
    }
    hipLaunchKernelGGL(crf_combine, dim3(Bn), dim3(128), 0, stream,
                       vws, Cws, numpart, cntpart, tags, em, startT, endT, out);
}

// Round 16
// 133.559 us; speedup vs baseline: 1.1048x; 1.1048x over previous
//
#include <hip/hip_runtime.h>
#include <hip/hip_bf16.h>

#define Tn 512
#define Bn 512
#define Kn 128
#define NUMCH 16    // numerator t-chunks (32 t each)

typedef __bf16 bf16_t;
typedef __bf16 bf16x8 __attribute__((ext_vector_type(8)));
typedef float f32x4 __attribute__((ext_vector_type(4)));
typedef unsigned int u32;
typedef u32 u32x2 __attribute__((ext_vector_type(2)));
typedef u32 u32x4 __attribute__((ext_vector_type(4)));

__device__ __forceinline__ u32 pack2bf(float a, float b) {
    bf16_t ha = (bf16_t)a, hb = (bf16_t)b;
    u32 ua = (u32)__builtin_bit_cast(unsigned short, ha);
    u32 ub = (u32)__builtin_bit_cast(unsigned short, hb);
    return ua | (ub << 16);
}

// ---------------- small pre: numerator partials (0..31, coalesced) +
//                  frag build (32..159) + out zeroing.  ~4us (r12-verified) ----------
// A-frag image: idx = (((dir*8 + m)*4 + ks)*64 + l)*8 + e
//   lane roles: c=l&15, g=l>>4;  k = 32*ks + 8*g + e
//   row j = J(m,c) = 32*(m>>1) + 4*(m&1) + 8*(c>>2) + (c&3)
//   dir 0 (fwd): A[j][k] = exp(trans[k][j]);  dir 1 (bwd): A[j][k] = exp(trans[j][k])
// J chosen so D's per-lane output IS the next step's B-frag layout (verified r1-r15).
__global__ __launch_bounds__(256)
void crf_small(const float* __restrict__ em, const int* __restrict__ tags,
               const int* __restrict__ mask, const float* __restrict__ trans,
               bf16_t* __restrict__ frags, float* __restrict__ numpart,
               int* __restrict__ cntpart, float* __restrict__ out)
{
    const int bid = blockIdx.x;
    const int tid = threadIdx.x;

    if (bid < 2*NUMCH) {               // ---- numerator partials, coalesced over b ----
        const int ch = bid >> 1, bh = bid & 1;
        const int b  = bh*256 + tid;   // lane-adjacent b -> coalesced mask/tags loads
        const int t0 = ch * (Tn / NUMCH);
        float s = 0.f;
        int cnt = 0;
        int tagprev = (t0 > 0) ? tags[(t0-1)*Bn + b] : 0;
        for (int t = t0; t < t0 + Tn/NUMCH; ++t) {
            const int mk = mask[t*Bn + b];
            const int tagcur = tags[t*Bn + b];
            if (mk != 0) {
                cnt++;
                if (t >= 1)
                    s += trans[tagprev*Kn + tagcur]
                       + em[(size_t)t*Bn*Kn + (size_t)b*Kn + tagcur];
            }
            tagprev = tagcur;
        }
        numpart[ch*Bn + b] = s;
        cntpart[ch*Bn + b] = cnt;
        return;
    }

    // ---- frag build: 128 blocks x 256 threads = 32768 elements ----
    const int b2 = bid - 2*NUMCH;
    if (b2 == 0 && tid == 0) out[0] = 0.f;
    const int idx = b2*256 + tid;
    const int e   = idx & 7;
    const int l   = (idx >> 3) & 63;
    const int ks  = (idx >> 9) & 3;
    const int m   = (idx >> 11) & 7;
    const int dir = (idx >> 14) & 1;
    const int c = l & 15, g = l >> 4;
    const int k = 32*ks + 8*g + e;
    const int j = 32*(m >> 1) + 4*(m & 1) + 8*(c >> 2) + (c & 3);
    const float v = (dir == 0) ? trans[k*Kn + j] : trans[j*Kn + k];
    frags[idx] = (bf16_t)__expf(v);
}

// ---------------- main: 8-wave j-split recurrence, PIPELINED in-loop exp -------------
// 64 blocks x 512 threads (8 waves = 2 waves/SIMD on 64 CUs). Wave mw owns m-tile mw
// (4 MFMA as 2 independent 2-chains + add), produces 4 j's/lane (u32x2 b64 write).
// State exchange: 8KB double-buffered LDS, one raw s_barrier/step.
// exp pipeline (3-stage): em loaded at iter m-2, exp'd at iter m-1 (placed under the
// ds_read latency shadow, OFF the MFMA->pack dependent tail), used at iter m.
// No X workspace, no expem kernel (X never paid: expem ~50us > 33us saved in main).
__global__ __launch_bounds__(512, 1)
void crf_main(const float* __restrict__ em, const int* __restrict__ maskp,
              const float* __restrict__ startT, const float* __restrict__ endT,
              const bf16_t* __restrict__ frags,
              float* __restrict__ vws, float* __restrict__ Cws)
{
    const int bid = blockIdx.x;          // 64 blocks
    const int dir = bid & 1;
    const int b0  = (bid >> 1) * 16;
    const int tid = threadIdx.x;
    const int mw  = tid >> 6;            // wave id = m-tile index 0..7
    const int l   = tid & 63;
    const int c = l & 15, g = l >> 4;
    const int batch = b0 + c;
    const int ksw  = mw >> 1, half = mw & 1;
    const int bj   = 32*ksw + 4*half;    // base j of own 4 outputs (plus 8g)

    __shared__ __align__(16) u32x4 exchg[2][4][64];   // [parity][slice][lane]

    // resident E fragments for own m-tile
    bf16x8 af[4];
    {
        const bf16_t* fb = frags + (size_t)dir * 16384;
        #pragma unroll
        for (int ks = 0; ks < 4; ++ks)
            af[ks] = *reinterpret_cast<const bf16x8*>(fb + ((mw*4 + ks)*64 + l)*8);
    }

    // init own state (+ bwd f32 state)
    f32x4 up;
    u32 ownprev0, ownprev1;
    float Cacc = 0.f;
    {
        const float* sv = dir ? endT : startT;
        const int t0 = dir ? 511 : 0;
        const f32x4 e4 = *reinterpret_cast<const f32x4*>(
            em + ((size_t)t0*Bn + batch)*Kn + bj + 8*g);
        const float* s4p = sv + bj + 8*g;
        f32x4 y;
        #pragma unroll
        for (int r = 0; r < 4; ++r) {
            const float s = s4p[r];
            y[r]  = __expf(s + e4[r]);
            up[r] = __expf(s);
        }
        ownprev0 = pack2bf(y[0], y[1]);
        ownprev1 = pack2bf(y[2], y[3]);
        u32* slot = reinterpret_cast<u32*>(&exchg[1][ksw][l]) + 2*half;
        u32x2 nw2 = {ownprev0, ownprev1};
        *reinterpret_cast<u32x2*>(slot) = nw2;   // iter m=1 reads parity 1
    }

    const int M = 256 - dir;

    // constant per-lane offsets (32-bit) + uniform t-offsets advanced on SALU
    const u32 laneE = (u32)((batch*Kn) + bj + 8*g);          // f32-index into em
    const u32 laneM = (u32)batch;                            // int-index into mask
    const long stepE = dir ? -(long)(2*Bn*Kn) : (long)(2*Bn*Kn);   // per 2t (f32 units)
    const long stepM = dir ? -(long)(2*Bn)    : (long)(2*Bn);      // per 2t (int units)
    long uEA, uEB, uMA, uMB;
    {
        const int tA  = dir ? 510 : 1, tB  = dir ? 509 : 2;
        const int tmA = dir ? 511 : 1, tmB = dir ? 510 : 2;
        uEA = (long)tA * (Bn*Kn);    uEB = (long)tB * (Bn*Kn);
        uMA = (long)tmA * Bn;        uMB = (long)tmB * Bn;
    }

    f32x4 emA, emB, xfA, xfB;    // 3-stage pipeline: load em -> exp -> use xf
    int mkA, mkB;
    auto load_tile = [&](f32x4& ed, int& mk, long& uE, long& uM) {
        ed = *reinterpret_cast<const f32x4*>(em + uE + laneE); uE += stepE;
        mk = maskp[uM + laneM]; uM += stepM;
    };

    // iter m: uses xfcur; computes xfoth = exp(emoth) (loaded iter m-1, issues under
    // the ds_read shadow); reloads emcur <- t(m+2).
    auto iter = [&](f32x4& xfcur, f32x4& emoth, f32x4& xfoth, int& mkcur,
                    long& uE, long& uM, bool rs, int par) {
        // release own write of previous step, sync, read full state
        asm volatile("s_waitcnt lgkmcnt(0)" ::: "memory");
        __builtin_amdgcn_s_barrier();
        __builtin_amdgcn_sched_barrier(0);

        const u32x4 bs0 = exchg[par][0][l];
        const u32x4 bs1 = exchg[par][1][l];
        const u32x4 bs2 = exchg[par][2][l];
        const u32x4 bs3 = exchg[par][3][l];

        // pipelined exp for NEXT iter: independent of this iter's MFMA chain,
        // placed here so it issues while the ds_reads are in flight.
        #pragma unroll
        for (int r = 0; r < 4; ++r) xfoth[r] = __expf(emoth[r]);

        // 2 independent MFMA chains of 2, then add (halves serial MFMA latency)
        f32x4 a0 = {0.f, 0.f, 0.f, 0.f}, a1 = {0.f, 0.f, 0.f, 0.f};
        a0 = __builtin_amdgcn_mfma_f32_16x16x32_bf16(af[0], __builtin_bit_cast(bf16x8, bs0), a0, 0, 0, 0);
        a1 = __builtin_amdgcn_mfma_f32_16x16x32_bf16(af[2], __builtin_bit_cast(bf16x8, bs2), a1, 0, 0, 0);
        a0 = __builtin_amdgcn_mfma_f32_16x16x32_bf16(af[1], __builtin_bit_cast(bf16x8, bs1), a0, 0, 0, 0);
        a1 = __builtin_amdgcn_mfma_f32_16x16x32_bf16(af[3], __builtin_bit_cast(bf16x8, bs3), a1, 0, 0, 0);
        const f32x4 acc = a0 + a1;

        const bool mk = (mkcur != 0);
        float sc = 1.f, klog = 0.f;
        if (rs) {   // exact pow-2 rescale; exponent of batch c's k=0 state component
            int ex = (int)((bs0[0] >> 7) & 0xFF) - 127;
            ex = __shfl(ex, c, 64);
            sc = __uint_as_float((u32)((127 - ex) & 0xFF) << 23);
            klog = (float)ex * 0.6931471805599453f;
        }

        u32 nw0, nw1;
        if (dir == 0) {  // fwd: v_t = (v@E)*x_t if mask else v
            f32x4 y;
            #pragma unroll
            for (int r = 0; r < 4; ++r) {
                float a = acc[r];
                if (rs) a *= sc;
                y[r] = a * xfcur[r];
            }
            nw0 = pack2bf(y[0], y[1]);
            nw1 = pack2bf(y[2], y[3]);
            nw0 = mk ? nw0 : ownprev0;
            nw1 = mk ? nw1 : ownprev1;
            ownprev0 = nw0; ownprev1 = nw1;
            if (rs && mk) Cacc += klog;
        } else {  // bwd: u = select(E@B, u); scale both branches; B = u*x_t
            f32x4 y;
            #pragma unroll
            for (int r = 0; r < 4; ++r) {
                float un = mk ? acc[r] : up[r];
                if (rs) un *= sc;
                up[r] = un;
                y[r] = un * xfcur[r];
            }
            nw0 = pack2bf(y[0], y[1]);
            nw1 = pack2bf(y[2], y[3]);
            if (rs) Cacc += klog;
        }

        u32* slot = reinterpret_cast<u32*>(&exchg[par ^ 1][ksw][l]) + 2*half;
        u32x2 nw2 = {nw0, nw1};
        *reinterpret_cast<u32x2*>(slot) = nw2;

        // reload this parity's em (t = m+2) + mask; exp'd next iter, used iter m+2
        f32x4 emcur_new;
        load_tile(emcur_new, mkcur, uE, uM);
        // overwrite the cur em buffer (xfcur already consumed above)
        // note: emcur aliases the caller's emA/emB via xf pairing; see call sites.
        (dir == dir) ? (void)0 : (void)0;  // no-op; emcur handled by caller binding
        emoth = emoth;                      // keep emoth live
        // store into the buffer paired with xfcur:
        *(&xfcur - &xfcur + (f32x4*)nullptr); // (removed below — see actual binding)
        __builtin_amdgcn_sched_barrier(0xF); // ALU/VALU/SALU/MFMA may cross; VMEM+DS pinned
    };

    // NOTE: the lambda above can't cleanly rebind emcur; use explicit A/B iters instead.
    (void)iter;

    auto iterAB = [&](f32x4& emcur, f32x4& xfcur, f32x4& emoth, f32x4& xfoth,
                      int& mkcur, long& uE, long& uM, bool rs, int par) {
        asm volatile("s_waitcnt lgkmcnt(0)" ::: "memory");
        __builtin_amdgcn_s_barrier();
        __builtin_amdgcn_sched_barrier(0);

        const u32x4 bs0 = exchg[par][0][l];
        const u32x4 bs1 = exchg[par][1][l];
        const u32x4 bs2 = exchg[par][2][l];
        const u32x4 bs3 = exchg[par][3][l];

        #pragma unroll
        for (int r = 0; r < 4; ++r) xfoth[r] = __expf(emoth[r]);  // pipelined exp

        f32x4 a0 = {0.f, 0.f, 0.f, 0.f}, a1 = {0.f, 0.f, 0.f, 0.f};
        a0 = __builtin_amdgcn_mfma_f32_16x16x32_bf16(af[0], __builtin_bit_cast(bf16x8, bs0), a0, 0, 0, 0);
        a1 = __builtin_amdgcn_mfma_f32_16x16x32_bf16(af[2], __builtin_bit_cast(bf16x8, bs2), a1, 0, 0, 0);
        a0 = __builtin_amdgcn_mfma_f32_16x16x32_bf16(af[1], __builtin_bit_cast(bf16x8, bs1), a0, 0, 0, 0);
        a1 = __builtin_amdgcn_mfma_f32_16x16x32_bf16(af[3], __builtin_bit_cast(bf16x8, bs3), a1, 0, 0, 0);
        const f32x4 acc = a0 + a1;

        const bool mk = (mkcur != 0);
        float sc = 1.f, klog = 0.f;
        if (rs) {
            int ex = (int)((bs0[0] >> 7) & 0xFF) - 127;
            ex = __shfl(ex, c, 64);
            sc = __uint_as_float((u32)((127 - ex) & 0xFF) << 23);
            klog = (float)ex * 0.6931471805599453f;
        }

        u32 nw0, nw1;
        if (dir == 0) {
            f32x4 y;
            #pragma unroll
            for (int r = 0; r < 4; ++r) {
                float a = acc[r];
                if (rs) a *= sc;
                y[r] = a * xfcur[r];
            }
            nw0 = pack2bf(y[0], y[1]);
            nw1 = pack2bf(y[2], y[3]);
            nw0 = mk ? nw0 : ownprev0;
            nw1 = mk ? nw1 : ownprev1;
            ownprev0 = nw0; ownprev1 = nw1;
            if (rs && mk) Cacc += klog;
        } else {
            f32x4 y;
            #pragma unroll
            for (int r = 0; r < 4; ++r) {
                float un = mk ? acc[r] : up[r];
                if (rs) un *= sc;
                up[r] = un;
                y[r] = un * xfcur[r];
            }
            nw0 = pack2bf(y[0], y[1]);
            nw1 = pack2bf(y[2], y[3]);
            if (rs) Cacc += klog;
        }

        u32* slot = reinterpret_cast<u32*>(&exchg[par ^ 1][ksw][l]) + 2*half;
        u32x2 nw2 = {nw0, nw1};
        *reinterpret_cast<u32x2*>(slot) = nw2;

        load_tile(emcur, mkcur, uE, uM);     // em <- t(m+2); exp'd next iter
        __builtin_amdgcn_sched_barrier(0xF); // VMEM+DS pinned at iteration boundary
    };

    load_tile(emA, mkA, uEA, uMA);           // t=1
    load_tile(emB, mkB, uEB, uMB);           // t=2
    #pragma unroll
    for (int r = 0; r < 4; ++r) xfA[r] = __expf(emA[r]);   // prologue exp (one stall)
    __builtin_amdgcn_sched_barrier(0xF);

    int m = 1;
    for (; m + 3 <= M; m += 4) {       // rs static: only (m+3)%4==0 rescales; par static
        iterAB(emA, xfA, emB, xfB, mkA, uEA, uMA, false, 1);
        iterAB(emB, xfB, emA, xfA, mkB, uEB, uMB, false, 0);
        iterAB(emA, xfA, emB, xfB, mkA, uEA, uMA, false, 1);
        iterAB(emB, xfB, emA, xfA, mkB, uEB, uMB, true,  0);
    }
    for (; m <= M; ++m) {              // bwd tail m=253..255 (never a rescale step)
        if (m & 1) iterAB(emA, xfA, emB, xfB, mkA, uEA, uMA, false, 1);
        else       iterAB(emB, xfB, emA, xfA, mkB, uEB, uMB, false, 0);
    }

    // final own state: fwd from ownprev regs, bwd from f32 up
    float* vrow = vws + ((size_t)(dir*Bn + batch))*Kn + bj + 8*g;
    f32x4 fv;
    if (dir) {
        fv = up;
    } else {
        fv[0] = __uint_as_float(ownprev0 << 16);
        fv[1] = __uint_as_float(ownprev0 & 0xffff0000u);
        fv[2] = __uint_as_float(ownprev1 << 16);
        fv[3] = __uint_as_float(ownprev1 & 0xffff0000u);
    }
    *reinterpret_cast<f32x4*>(vrow) = fv;
    if (mw == 0 && g == 0) Cws[dir*Bn + batch] = Cacc;
}

// ---------------- combine: numerator finalize + den + out accumulation ----------------
__global__ void crf_combine(const float* __restrict__ vws, const float* __restrict__ Cws,
                            const float* __restrict__ numpart, const int* __restrict__ cntpart,
                            const int* __restrict__ tags, const float* __restrict__ em,
                            const float* __restrict__ startT, const float* __restrict__ endT,
                            float* __restrict__ out)
{
    const int b = blockIdx.x;
    const int tid = threadIdx.x;
    const float p = vws[(size_t)b*Kn + tid] * vws[(size_t)(Bn + b)*Kn + tid];
    __shared__ float red[128];
    __shared__ float sp[NUMCH];
    __shared__ int   cp[NUMCH];
    red[tid] = p;
    if (tid < NUMCH) { sp[tid] = numpart[tid*Bn + b]; cp[tid] = cntpart[tid*Bn + b]; }
    __syncthreads();
    for (int off = 64; off > 0; off >>= 1) {
        if (tid < off) red[tid] += red[tid + off];
        __syncthreads();
    }
    if (tid == 0) {
        float s = 0.f; int cnt = 0;
        #pragma unroll
        for (int ch = 0; ch < NUMCH; ++ch) { s += sp[ch]; cnt += cp[ch]; }
        const int t0tag = tags[b];
        int seq_end = cnt - 1;
        if (seq_end < 0) seq_end = 0;
        const int lastTag = tags[seq_end*Bn + b];
        const float num = startT[t0tag] + em[(size_t)b*Kn + t0tag] + s + endT[lastTag];
        const float den = Cws[b] + Cws[Bn + b] + logf(red[0]);
        atomicAdd(out, num - den);
    }
}

extern "C" void kernel_launch(void* const* d_in, const int* in_sizes, int n_in,
                              void* d_out, int out_size, void* d_ws, size_t ws_size,
                              hipStream_t stream)
{
    const float* em     = (const float*)d_in[0];
    const int*   tags   = (const int*)d_in[1];
    const int*   mask   = (const int*)d_in[2];
    const float* startT = (const float*)d_in[3];
    const float* endT   = (const float*)d_in[4];
    const float* trans  = (const float*)d_in[5];

    char* ws = (char*)d_ws;
    bf16_t* frags   = (bf16_t*)ws;                    // 65536 B
    float*  Cws     = (float*)(ws + 65536);           // 4096 B
    float*  vws     = (float*)(ws + 69632);           // 524288 B
    float*  numpart = (float*)(ws + 593920);          // 32768 B
    int*    cntpart = (int*)(ws + 626688);            // 32768 B
    float*  out     = (float*)d_out;

    hipLaunchKernelGGL(crf_small, dim3(2*NUMCH + 128), dim3(256), 0, stream,
                       em, tags, mask, trans, frags, numpart, cntpart, out);
    hipLaunchKernelGGL(crf_main, dim3(64), dim3(512), 0, stream,
                       em, mask, startT, endT, frags, vws, Cws);
    hipLaunchKernelGGL(crf_combine, dim3(Bn), dim3(128), 0, stream,
                       vws, Cws, numpart, cntpart, tags, em, startT, endT, out);
}

// Round 17
// 124.921 us; speedup vs baseline: 1.1812x; 1.0691x over previous
//
#include <hip/hip_runtime.h>
#include <hip/hip_bf16.h>

#define Tn 512
#define Bn 512
#define Kn 128
#define NUMCH 16    // numerator t-chunks (32 t each)

typedef __bf16 bf16_t;
typedef __bf16 bf16x8 __attribute__((ext_vector_type(8)));
typedef float f32x4 __attribute__((ext_vector_type(4)));
typedef unsigned int u32;
typedef u32 u32x2 __attribute__((ext_vector_type(2)));
typedef u32 u32x4 __attribute__((ext_vector_type(4)));

__device__ __forceinline__ u32 pack2bf(float a, float b) {
    bf16_t ha = (bf16_t)a, hb = (bf16_t)b;
    u32 ua = (u32)__builtin_bit_cast(unsigned short, ha);
    u32 ub = (u32)__builtin_bit_cast(unsigned short, hb);
    return ua | (ub << 16);
}

// ---------------- small pre: numerator partials (0..31, coalesced) +
//                  frag build (32..159) + out zeroing.  ~4us (r12-verified) ----------
// A-frag image: idx = (((dir*8 + m)*4 + ks)*64 + l)*8 + e
//   lane roles: c=l&15, g=l>>4;  k = 32*ks + 8*g + e
//   row j = J(m,c) = 32*(m>>1) + 4*(m&1) + 8*(c>>2) + (c&3)
//   dir 0 (fwd): A[j][k] = exp(trans[k][j]);  dir 1 (bwd): A[j][k] = exp(trans[j][k])
// J chosen so D's per-lane output IS the next step's B-frag layout (verified r1-r16).
__global__ __launch_bounds__(256)
void crf_small(const float* __restrict__ em, const int* __restrict__ tags,
               const int* __restrict__ mask, const float* __restrict__ trans,
               bf16_t* __restrict__ frags, float* __restrict__ numpart,
               int* __restrict__ cntpart, float* __restrict__ out)
{
    const int bid = blockIdx.x;
    const int tid = threadIdx.x;

    if (bid < 2*NUMCH) {               // ---- numerator partials, coalesced over b ----
        const int ch = bid >> 1, bh = bid & 1;
        const int b  = bh*256 + tid;   // lane-adjacent b -> coalesced mask/tags loads
        const int t0 = ch * (Tn / NUMCH);
        float s = 0.f;
        int cnt = 0;
        int tagprev = (t0 > 0) ? tags[(t0-1)*Bn + b] : 0;
        for (int t = t0; t < t0 + Tn/NUMCH; ++t) {
            const int mk = mask[t*Bn + b];
            const int tagcur = tags[t*Bn + b];
            if (mk != 0) {
                cnt++;
                if (t >= 1)
                    s += trans[tagprev*Kn + tagcur]
                       + em[(size_t)t*Bn*Kn + (size_t)b*Kn + tagcur];
            }
            tagprev = tagcur;
        }
        numpart[ch*Bn + b] = s;
        cntpart[ch*Bn + b] = cnt;
        return;
    }

    // ---- frag build: 128 blocks x 256 threads = 32768 elements ----
    const int b2 = bid - 2*NUMCH;
    if (b2 == 0 && tid == 0) out[0] = 0.f;
    const int idx = b2*256 + tid;
    const int e   = idx & 7;
    const int l   = (idx >> 3) & 63;
    const int ks  = (idx >> 9) & 3;
    const int m   = (idx >> 11) & 7;
    const int dir = (idx >> 14) & 1;
    const int c = l & 15, g = l >> 4;
    const int k = 32*ks + 8*g + e;
    const int j = 32*(m >> 1) + 4*(m & 1) + 8*(c >> 2) + (c & 3);
    const float v = (dir == 0) ? trans[k*Kn + j] : trans[j*Kn + k];
    frags[idx] = (bf16_t)__expf(v);
}

// ---------------- main: 256-block 8-wave j-split recurrence (r12 body) --------------
// 256 blocks x 512 threads: 128 groups x 4 batches x 2 dirs -> FULL chip (was 64 CUs).
// Lanes c>=4 duplicate batch c&3 (bit-identical math; duplicate stores masked off).
// Per-block em traffic drops 8KB -> 2KB/step at constant total work: A/B test of the
// per-block memory-return-rate hypothesis (r12 1060cy/step @8KB vs r15 754cy @4KB).
// Wave mw owns m-tile mw (4 MFMA as 2 independent 2-chains + add); state exchange via
// 8KB double-buffered LDS, one raw s_barrier/step; SALU uniform t-offsets; in-loop exp.
__global__ __launch_bounds__(512, 1)
void crf_main(const float* __restrict__ em, const int* __restrict__ maskp,
              const float* __restrict__ startT, const float* __restrict__ endT,
              const bf16_t* __restrict__ frags,
              float* __restrict__ vws, float* __restrict__ Cws)
{
    const int bid = blockIdx.x;          // 256 blocks
    const int dir = bid & 1;
    const int b0  = (bid >> 1) * 4;      // 4-batch group
    const int tid = threadIdx.x;
    const int mw  = tid >> 6;            // wave id = m-tile index 0..7
    const int l   = tid & 63;
    const int c = l & 15, g = l >> 4;
    const int batch = b0 + (c & 3);      // lanes c>=4 duplicate batch c&3
    const int ksw  = mw >> 1, half = mw & 1;
    const int bj   = 32*ksw + 4*half;    // base j of own 4 outputs (plus 8g)

    __shared__ __align__(16) u32x4 exchg[2][4][64];   // [parity][slice][lane]

    // resident E fragments for own m-tile
    bf16x8 af[4];
    {
        const bf16_t* fb = frags + (size_t)dir * 16384;
        #pragma unroll
        for (int ks = 0; ks < 4; ++ks)
            af[ks] = *reinterpret_cast<const bf16x8*>(fb + ((mw*4 + ks)*64 + l)*8);
    }

    // init own state (+ bwd f32 state)
    f32x4 up;
    u32 ownprev0, ownprev1;
    float Cacc = 0.f;
    {
        const float* sv = dir ? endT : startT;
        const int t0 = dir ? 511 : 0;
        const f32x4 e4 = *reinterpret_cast<const f32x4*>(
            em + ((size_t)t0*Bn + batch)*Kn + bj + 8*g);
        const float* s4p = sv + bj + 8*g;
        f32x4 y;
        #pragma unroll
        for (int r = 0; r < 4; ++r) {
            const float s = s4p[r];
            y[r]  = __expf(s + e4[r]);
            up[r] = __expf(s);
        }
        ownprev0 = pack2bf(y[0], y[1]);
        ownprev1 = pack2bf(y[2], y[3]);
        u32* slot = reinterpret_cast<u32*>(&exchg[1][ksw][l]) + 2*half;
        u32x2 nw2 = {ownprev0, ownprev1};
        *reinterpret_cast<u32x2*>(slot) = nw2;   // iter m=1 reads parity 1
    }

    const int M = 256 - dir;

    // constant per-lane offsets (32-bit) + uniform t-offsets advanced on SALU
    const u32 laneE = (u32)((batch*Kn) + bj + 8*g);          // f32-index into em
    const u32 laneM = (u32)batch;                            // int-index into mask
    const long stepE = dir ? -(long)(2*Bn*Kn) : (long)(2*Bn*Kn);   // per 2t (f32 units)
    const long stepM = dir ? -(long)(2*Bn)    : (long)(2*Bn);      // per 2t (int units)
    long uEA, uEB, uMA, uMB;
    {
        const int tA  = dir ? 510 : 1, tB  = dir ? 509 : 2;
        const int tmA = dir ? 511 : 1, tmB = dir ? 510 : 2;
        uEA = (long)tA * (Bn*Kn);    uEB = (long)tB * (Bn*Kn);
        uMA = (long)tmA * Bn;        uMB = (long)tmB * Bn;
    }

    f32x4 eA, eB; int mkA, mkB;
    auto load_tile = [&](f32x4& ed, int& mk, long& uE, long& uM) {
        ed = *reinterpret_cast<const f32x4*>(em + uE + laneE); uE += stepE;
        mk = maskp[uM + laneM]; uM += stepM;
    };

    auto iter = [&](f32x4& ecur, int& mkcur, long& uE, long& uM, bool rs, int par) {
        // release own write of previous step, sync, read full state
        asm volatile("s_waitcnt lgkmcnt(0)" ::: "memory");
        __builtin_amdgcn_s_barrier();
        __builtin_amdgcn_sched_barrier(0);

        const u32x4 bs0 = exchg[par][0][l];
        const u32x4 bs1 = exchg[par][1][l];
        const u32x4 bs2 = exchg[par][2][l];
        const u32x4 bs3 = exchg[par][3][l];

        // 2 independent MFMA chains of 2, then add (halves serial MFMA latency)
        f32x4 a0 = {0.f, 0.f, 0.f, 0.f}, a1 = {0.f, 0.f, 0.f, 0.f};
        a0 = __builtin_amdgcn_mfma_f32_16x16x32_bf16(af[0], __builtin_bit_cast(bf16x8, bs0), a0, 0, 0, 0);
        a1 = __builtin_amdgcn_mfma_f32_16x16x32_bf16(af[2], __builtin_bit_cast(bf16x8, bs2), a1, 0, 0, 0);
        a0 = __builtin_amdgcn_mfma_f32_16x16x32_bf16(af[1], __builtin_bit_cast(bf16x8, bs1), a0, 0, 0, 0);
        a1 = __builtin_amdgcn_mfma_f32_16x16x32_bf16(af[3], __builtin_bit_cast(bf16x8, bs3), a1, 0, 0, 0);
        const f32x4 acc = a0 + a1;

        const bool mk = (mkcur != 0);
        float sc = 1.f, klog = 0.f;
        if (rs) {   // exact pow-2 rescale; exponent of batch c's k=0 state component
            int ex = (int)((bs0[0] >> 7) & 0xFF) - 127;
            ex = __shfl(ex, c, 64);
            sc = __uint_as_float((u32)((127 - ex) & 0xFF) << 23);
            klog = (float)ex * 0.6931471805599453f;
        }

        f32x4 xf;
        #pragma unroll
        for (int r = 0; r < 4; ++r) xf[r] = __expf(ecur[r]);

        u32 nw0, nw1;
        if (dir == 0) {  // fwd: v_t = (v@E)*x_t if mask else v
            f32x4 y;
            #pragma unroll
            for (int r = 0; r < 4; ++r) {
                float a = acc[r];
                if (rs) a *= sc;
                y[r] = a * xf[r];
            }
            nw0 = pack2bf(y[0], y[1]);
            nw1 = pack2bf(y[2], y[3]);
            nw0 = mk ? nw0 : ownprev0;
            nw1 = mk ? nw1 : ownprev1;
            ownprev0 = nw0; ownprev1 = nw1;
            if (rs && mk) Cacc += klog;
        } else {  // bwd: u = select(E@B, u); scale both branches; B = u*x_t
            f32x4 y;
            #pragma unroll
            for (int r = 0; r < 4; ++r) {
                float un = mk ? acc[r] : up[r];
                if (rs) un *= sc;
                up[r] = un;
                y[r] = un * xf[r];
            }
            nw0 = pack2bf(y[0], y[1]);
            nw1 = pack2bf(y[2], y[3]);
            if (rs) Cacc += klog;
        }

        u32* slot = reinterpret_cast<u32*>(&exchg[par ^ 1][ksw][l]) + 2*half;
        u32x2 nw2 = {nw0, nw1};
        *reinterpret_cast<u32x2*>(slot) = nw2;

        load_tile(ecur, mkcur, uE, uM);
        __builtin_amdgcn_sched_barrier(0xF); // ALU/VALU/SALU/MFMA may cross; VMEM+DS pinned
    };

    load_tile(eA, mkA, uEA, uMA);
    load_tile(eB, mkB, uEB, uMB);
    __builtin_amdgcn_sched_barrier(0xF);

    int m = 1;
    for (; m + 3 <= M; m += 4) {       // rs static: only (m+3)%4==0 rescales; par static
        iter(eA, mkA, uEA, uMA, false, 1);
        iter(eB, mkB, uEB, uMB, false, 0);
        iter(eA, mkA, uEA, uMA, false, 1);
        iter(eB, mkB, uEB, uMB, true,  0);
    }
    for (; m <= M; ++m) {              // bwd tail m=253..255 (never a rescale step)
        if (m & 1) iter(eA, mkA, uEA, uMA, false, 1);
        else       iter(eB, mkB, uEB, uMB, false, 0);
    }

    // final own state: fwd from ownprev regs, bwd from f32 up.
    // Only lanes c<4 store (c>=4 are duplicates of batch c&3).
    if ((c >> 2) == 0) {
        float* vrow = vws + ((size_t)(dir*Bn + batch))*Kn + bj + 8*g;
        f32x4 fv;
        if (dir) {
            fv = up;
        } else {
            fv[0] = __uint_as_float(ownprev0 << 16);
            fv[1] = __uint_as_float(ownprev0 & 0xffff0000u);
            fv[2] = __uint_as_float(ownprev1 << 16);
            fv[3] = __uint_as_float(ownprev1 & 0xffff0000u);
        }
        *reinterpret_cast<f32x4*>(vrow) = fv;
        if (mw == 0 && g == 0) Cws[dir*Bn + batch] = Cacc;
    }
}

// ---------------- combine: numerator finalize + den + out accumulation ----------------
__global__ void crf_combine(const float* __restrict__ vws, const float* __restrict__ Cws,
                            const float* __restrict__ numpart, const int* __restrict__ cntpart,
                            const int* __restrict__ tags, const float* __restrict__ em,
                            const float* __restrict__ startT, const float* __restrict__ endT,
                            float* __restrict__ out)
{
    const int b = blockIdx.x;
    const int tid = threadIdx.x;
    const float p = vws[(size_t)b*Kn + tid] * vws[(size_t)(Bn + b)*Kn + tid];
    __shared__ float red[128];
    __shared__ float sp[NUMCH];
    __shared__ int   cp[NUMCH];
    red[tid] = p;
    if (tid < NUMCH) { sp[tid] = numpart[tid*Bn + b]; cp[tid] = cntpart[tid*Bn + b]; }
    __syncthreads();
    for (int off = 64; off > 0; off >>= 1) {
        if (tid < off) red[tid] += red[tid + off];
        __syncthreads();
    }
    if (tid == 0) {
        float s = 0.f; int cnt = 0;
        #pragma unroll
        for (int ch = 0; ch < NUMCH; ++ch) { s += sp[ch]; cnt += cp[ch]; }
        const int t0tag = tags[b];
        int seq_end = cnt - 1;
        if (seq_end < 0) seq_end = 0;
        const int lastTag = tags[seq_end*Bn + b];
        const float num = startT[t0tag] + em[(size_t)b*Kn + t0tag] + s + endT[lastTag];
        const float den = Cws[b] + Cws[Bn + b] + logf(red[0]);
        atomicAdd(out, num - den);
    }
}

extern "C" void kernel_launch(void* const* d_in, const int* in_sizes, int n_in,
                              void* d_out, int out_size, void* d_ws, size_t ws_size,
                              hipStream_t stream)
{
    const float* em     = (const float*)d_in[0];
    const int*   tags   = (const int*)d_in[1];
    const int*   mask   = (const int*)d_in[2];
    const float* startT = (const float*)d_in[3];
    const float* endT   = (const float*)d_in[4];
    const float* trans  = (const float*)d_in[5];

    char* ws = (char*)d_ws;
    bf16_t* frags   = (bf16_t*)ws;                    // 65536 B
    float*  Cws     = (float*)(ws + 65536);           // 4096 B
    float*  vws     = (float*)(ws + 69632);           // 524288 B
    float*  numpart = (float*)(ws + 593920);          // 32768 B
    int*    cntpart = (int*)(ws + 626688);            // 32768 B
    float*  out     = (float*)d_out;

    hipLaunchKernelGGL(crf_small, dim3(2*NUMCH + 128), dim3(256), 0, stream,
                       em, tags, mask, trans, frags, numpart, cntpart, out);
    hipLaunchKernelGGL(crf_main, dim3(256), dim3(512), 0, stream,
                       em, mask, startT, endT, frags, vws, Cws);
    hipLaunchKernelGGL(crf_combine, dim3(Bn), dim3(128), 0, stream,
                       vws, Cws, numpart, cntpart, tags, em, startT, endT, out);
}